// Round 15
// baseline (1092.847 us; speedup 1.0000x reference)
//
#include <hip/hip_runtime.h>

#define NN 10000
#define NE 320000

typedef float f4 __attribute__((ext_vector_type(4)));
typedef float f32x4 __attribute__((ext_vector_type(4)));
typedef short bf16x8 __attribute__((ext_vector_type(8)));

__device__ __forceinline__ unsigned short f2b(float f) {
  unsigned u = __float_as_uint(f);
  u += 0x7fff + ((u >> 16) & 1);          // RNE
  return (unsigned short)(u >> 16);
}
__device__ __forceinline__ float b2f(unsigned short s) {
  return __uint_as_float(((unsigned)s) << 16);
}
__device__ __forceinline__ bf16x8 pack8(f4 a, f4 b) {
  bf16x8 r;
  r[0] = (short)f2b(a[0]); r[1] = (short)f2b(a[1]);
  r[2] = (short)f2b(a[2]); r[3] = (short)f2b(a[3]);
  r[4] = (short)f2b(b[0]); r[5] = (short)f2b(b[1]);
  r[6] = (short)f2b(b[2]); r[7] = (short)f2b(b[3]);
  return r;
}
// swizzled ushort index into a flat [64][256] bf16 tile (XOR bank swizzle)
__device__ __forceinline__ int swz(int row, int k) {
  return (row * 256) + (k ^ ((row & 7) << 3));
}

// transpose+cast weights: in f32 [K][N] -> out bf16 [N][K]
__global__ void castw_k(const float* __restrict__ in, unsigned short* __restrict__ out,
                        int K, int lg)
{
  int idx = blockIdx.x * 256 + threadIdx.x;
  if (idx >= (K << lg)) return;
  int n = idx & ((1 << lg) - 1), k = idx >> lg;
  out[(size_t)n * K + k] = f2b(in[idx]);
}

// contiguous f32 -> bf16 cast (8 elems/thread)
__global__ void castb_k(const float* __restrict__ in, unsigned short* __restrict__ out,
                        long n8)
{
  long i = (long)blockIdx.x * 256 + threadIdx.x;
  if (i >= n8) return;
  const f4* p = (const f4*)(in + i * 8);
  *(bf16x8*)(out + i * 8) = pack8(p[0], p[1]);
}

__global__ void cat3_k(const float* __restrict__ a, const float* __restrict__ b,
                       const float* __restrict__ c, float* __restrict__ o)
{
  int t = threadIdx.x;
  o[t] = a[t]; o[256 + t] = b[t]; o[512 + t] = c[t];
}

// Generic node-side MFMA GEMM: C[M,N] = act(castbf16(A[M,K]) @ BT^T + bias (+res))
__global__ __launch_bounds__(256) void gemm_bf16_k(
    const float* __restrict__ A, const unsigned short* __restrict__ BT,
    const float* __restrict__ bias, const float* __restrict__ res,
    float* __restrict__ C, float* __restrict__ stats,
    int M, int K, int NT, int flags)
{
  __shared__ unsigned short Al[64][40];
  __shared__ unsigned short Bl[128][40];
  const int t = threadIdx.x;
  const int n0 = blockIdx.x * 128;
  const int m0 = blockIdx.y * 64;
  const int lane = t & 63, c = lane & 15, g = lane >> 4, w = t >> 6;
  f32x4 acc[8] = {};
  for (int k0 = 0; k0 < K; k0 += 32) {
    {
      int row = t >> 2, kk = (t & 3) * 8;
      f4 v0 = {0.f,0.f,0.f,0.f}, v1 = {0.f,0.f,0.f,0.f};
      if (m0 + row < M) {
        const f4* p = (const f4*)(A + (size_t)(m0 + row) * K + k0 + kk);
        v0 = p[0]; v1 = p[1];
      }
      __syncthreads();
      *(bf16x8*)&Al[row][kk] = pack8(v0, v1);
    }
    {
      int col = t >> 1, kk = (t & 1) * 16;
      const bf16x8* p = (const bf16x8*)(BT + (size_t)(n0 + col) * K + k0 + kk);
      *(bf16x8*)&Bl[col][kk] = p[0];
      *(bf16x8*)&Bl[col][kk + 8] = p[1];
    }
    __syncthreads();
    bf16x8 a = *(bf16x8*)&Al[w * 16 + c][g * 8];
#pragma unroll
    for (int nb = 0; nb < 8; nb++) {
      bf16x8 b = *(bf16x8*)&Bl[nb * 16 + c][g * 8];
      acc[nb] = __builtin_amdgcn_mfma_f32_16x16x32_bf16(a, b, acc[nb], 0, 0, 0);
    }
  }
  const int do_relu = flags & 1, do_stats = flags & 2;
#pragma unroll
  for (int nb = 0; nb < 8; nb++) {
    const int col = n0 + nb * 16 + c;
    const float bs = bias[col];
    float sn = 0.f, qn = 0.f;
#pragma unroll
    for (int r = 0; r < 4; r++) {
      int row = m0 + w * 16 + g * 4 + r;
      if (row < M) {
        float v = acc[nb][r] + bs;
        if (res) v += res[(size_t)row * NT + col];
        if (do_relu) v = fmaxf(v, 0.f);
        C[(size_t)row * NT + col] = v;
        sn += v; qn += v * v;
      }
    }
    if (do_stats) {
      sn += __shfl_xor(sn, 16); sn += __shfl_xor(sn, 32);
      qn += __shfl_xor(qn, 16); qn += __shfl_xor(qn, 32);
      if (g == 0) {
        atomicAdd(&stats[col], sn);
        atomicAdd(&stats[NT + col], qn);
      }
    }
  }
}

// Edge kernel v8: 128 edges/block (two 64-row A halves in registers, 64+64
// VGPR fragments); per head ONE B-stage feeds 64 MFMAs + two in-register
// epilogues. 41KB LDS -> 3 blocks/CU; barriers/edge halved vs v6.
__global__ __launch_bounds__(256, 3) void edge_conn_k(
    const float* __restrict__ EA, const unsigned short* __restrict__ EwT,
    const float* __restrict__ Eb, const unsigned short* __restrict__ QKVb,
    const int* __restrict__ ei, const float* __restrict__ Aw,
    float* __restrict__ connf, unsigned short* __restrict__ connb,
    float* __restrict__ score, int CB)
{
  __shared__ unsigned short sh[16384];     // 32KB: A staging (x2), then B per head
  __shared__ unsigned short ExlB[64 * 72]; // 9KB bf16 transpose buffer (reused per half)
  const int t = threadIdx.x;
  const int e0 = blockIdx.x * 128;
  const int lane = t & 63, c = lane & 15, g = lane >> 4, w = t >> 6;
  const int m2 = t >> 2, dg = t & 3;

  bf16x8 areg[2][8];
  int esrc[2], edst[2];
#pragma unroll
  for (int u = 0; u < 2; u++) {
    // stage A half u (64 rows) coalesced as bf16, swizzled
#pragma unroll
    for (int it = 0; it < 8; it++) {
      int o = t + it * 256;
      int row = o >> 5, kk = (o & 31) * 8;
      const f4* p = (const f4*)(EA + (size_t)(e0 + u * 64 + row) * 256 + kk);
      f4 v0 = p[0], v1 = p[1];
      *(bf16x8*)&sh[swz(row, kk)] = pack8(v0, v1);
    }
    esrc[u] = ei[e0 + u * 64 + m2];
    edst[u] = ei[NE + e0 + u * 64 + m2];
    __syncthreads();   // A half staged
#pragma unroll
    for (int i = 0; i < 8; i++)
      areg[u][i] = *(bf16x8*)&sh[swz(w * 16 + c, i * 32 + g * 8)];
    __syncthreads();   // reads done; sh reusable
  }

  for (int h = 0; h < 8; h++) {
    // prefetch K/Q for this head, both halves
    bf16x8 kv8[2], qv8[2];
#pragma unroll
    for (int u = 0; u < 2; u++) {
      kv8[u] = *(const bf16x8*)(QKVb + (size_t)esrc[u] * 768 + 256 + h * 32 + dg * 8);
      qv8[u] = *(const bf16x8*)(QKVb + (size_t)edst[u] * 768 + h * 32 + dg * 8);
    }
    // stage B (EwT rows for head h) into sh
#pragma unroll
    for (int it = 0; it < 8; it++) {
      int o = t + it * 256;
      int row = o >> 5, kk = (o & 31) * 8;
      *(bf16x8*)&sh[swz(row, kk)] =
          *(const bf16x8*)(EwT + (size_t)(h * 64 + row) * 256 + kk);
    }
    __syncthreads();   // B ready
    f32x4 acc[2][4];
#pragma unroll
    for (int u = 0; u < 2; u++)
#pragma unroll
      for (int cb = 0; cb < 4; cb++)
#pragma unroll
        for (int z = 0; z < 4; z++) acc[u][cb][z] = 0.f;
#pragma unroll
    for (int ks = 0; ks < 8; ks++) {
#pragma unroll
      for (int cb = 0; cb < 4; cb++) {
        bf16x8 b = *(bf16x8*)&sh[swz(cb * 16 + c, ks * 32 + g * 8)];
        acc[0][cb] = __builtin_amdgcn_mfma_f32_16x16x32_bf16(areg[0][ks], b, acc[0][cb], 0, 0, 0);
        acc[1][cb] = __builtin_amdgcn_mfma_f32_16x16x32_bf16(areg[1][ks], b, acc[1][cb], 0, 0, 0);
      }
    }
#pragma unroll
    for (int u = 0; u < 2; u++) {
      // write Ex (bf16) into ExlB -- intra-wave only, no barrier
#pragma unroll
      for (int cb = 0; cb < 4; cb++) {
        float eb = Eb[h * 64 + cb * 16 + c];
#pragma unroll
        for (int r = 0; r < 4; r++)
          ExlB[(w * 16 + g * 4 + r) * 72 + cb * 16 + c] = f2b(acc[u][cb][r] + eb);
      }
      // epilogue: conn + score for head h, half u (reads own wave's rows)
      const int e = e0 + u * 64 + m2;
      bf16x8 x1 = *(bf16x8*)&ExlB[m2 * 72 + dg * 8];
      bf16x8 x2 = *(bf16x8*)&ExlB[m2 * 72 + 32 + dg * 8];
      const int cb2 = h * 32 + dg * 8;
      f4 c1, c2;
      float part = 0.f;
#pragma unroll
      for (int j = 0; j < 4; j++) {
        float ex1 = b2f((unsigned short)x1[j]);
        float ex2 = b2f((unsigned short)x2[j]);
        float s2 = ex1 * ex2;
        float v = copysignf(sqrtf(fabsf(s2)), s2)
                + b2f((unsigned short)kv8[u][j]) + b2f((unsigned short)qv8[u][j]);
        v = fmaxf(v, 0.f);
        c1[j] = v;
        part += v * Aw[(dg * 8 + j) * 8 + h];
        float ex1b = b2f((unsigned short)x1[j + 4]);
        float ex2b = b2f((unsigned short)x2[j + 4]);
        float s2b = ex1b * ex2b;
        float vb = copysignf(sqrtf(fabsf(s2b)), s2b)
                 + b2f((unsigned short)kv8[u][j + 4]) + b2f((unsigned short)qv8[u][j + 4]);
        vb = fmaxf(vb, 0.f);
        c2[j] = vb;
        part += vb * Aw[(dg * 8 + 4 + j) * 8 + h];
      }
      if (CB) {
        *(bf16x8*)(connb + (size_t)e * 256 + cb2) = pack8(c1, c2);  // 16B store
      } else {
        *(f4*)(connf + (size_t)e * 256 + cb2) = c1;
        *(f4*)(connf + (size_t)e * 256 + cb2 + 4) = c2;
      }
      part += __shfl_xor(part, 1);
      part += __shfl_xor(part, 2);
      if (dg == 0) score[(size_t)e * 8 + h] = fminf(fmaxf(part, -5.f), 5.f);
    }
    __syncthreads();   // all MFMA reads of sh done before next head's restage
  }
}

// ---------- CSR build (by destination) ----------
__global__ void hist_k(const int* __restrict__ ei, int* __restrict__ cnt)
{
  int e = blockIdx.x * 256 + threadIdx.x;
  if (e < NE) atomicAdd(&cnt[ei[NE + e]], 1);
}

__global__ __launch_bounds__(256) void scan_k(const int* __restrict__ cnt, int* __restrict__ off)
{
  __shared__ int part[256];
  const int t = threadIdx.x;
  const int PER = 40;
  const int base = t * PER;
  int s = 0;
  for (int i = 0; i < PER; i++) {
    int b = base + i;
    if (b < NN) s += cnt[b];
  }
  part[t] = s;
  __syncthreads();
  for (int d = 1; d < 256; d <<= 1) {
    int v = (t >= d) ? part[t - d] : 0;
    __syncthreads();
    part[t] += v;
    __syncthreads();
  }
  int run = (t == 0) ? 0 : part[t - 1];
  for (int i = 0; i < PER; i++) {
    int b = base + i;
    if (b < NN) { off[b] = run; run += cnt[b]; }
  }
  if (t == 255) off[NN] = run;
}

__global__ void scat_k(const int* __restrict__ ei, const int* __restrict__ off,
                       int* __restrict__ cur, int* __restrict__ elist,
                       int* __restrict__ src_s)
{
  int e = blockIdx.x * 256 + threadIdx.x;
  if (e < NE) {
    int s = ei[e], d = ei[NE + e];
    int p = atomicAdd(&cur[d], 1);
    int j = off[d] + p;
    elist[j] = e;
    src_s[j] = s;
  }
}

// One block per node: online segment softmax (parallel max/exp) + weighted
// aggregation + rowV einsum + degree scaler. V gathered from bf16 mirror.
__global__ __launch_bounds__(256) void node_agg_k(
    const int* __restrict__ off, const int* __restrict__ elist,
    const int* __restrict__ src_s, const float* __restrict__ score,
    const float* __restrict__ QKVh, const unsigned short* __restrict__ QKVb,
    const float* __restrict__ connf, const unsigned short* __restrict__ connb, int CB,
    const float* __restrict__ VeRow, const float* __restrict__ deg_coef,
    const float* __restrict__ log_deg, float* __restrict__ nh_a)
{
  const int n = blockIdx.x, t = threadIdx.x;
  const int h = t >> 5;
  __shared__ int eL[128];
  __shared__ int srcL[128];
  __shared__ float sS[1024];
  __shared__ float mS[8];
  __shared__ float rA[256];
  const int start = off[n];
  const int deg = off[n + 1] - start;
  float m = -1e30f, ssum = 0.f, vo = 0.f, ro = 0.f;
  for (int c0 = 0; c0 < deg; c0 += 128) {
    const int cn = min(128, deg - c0);
    __syncthreads();
    if (t < cn) {
      int jj = start + c0 + t;
      eL[t] = elist[jj];
      srcL[t] = src_s[jj];
    }
    __syncthreads();
    for (int i = t; i < cn * 8; i += 256) sS[i] = score[(size_t)eL[i >> 3] * 8 + (i & 7)];
    __syncthreads();
    float mc = -1e30f;
    for (int i = (t & 31); i < cn; i += 32) mc = fmaxf(mc, sS[i * 8 + h]);
    mc = fmaxf(mc, __shfl_xor(mc, 1));
    mc = fmaxf(mc, __shfl_xor(mc, 2));
    mc = fmaxf(mc, __shfl_xor(mc, 4));
    mc = fmaxf(mc, __shfl_xor(mc, 8));
    mc = fmaxf(mc, __shfl_xor(mc, 16));
    float nm = fmaxf(m, mc);
    if ((t & 31) == 0) mS[h] = nm;
    __syncthreads();
    for (int i = t; i < cn * 8; i += 256) sS[i] = __expf(sS[i] - mS[i & 7]);
    __syncthreads();
    float sc = __expf(m - nm);
    ssum *= sc; vo *= sc; ro *= sc;
    m = nm;
    int i = 0;
    if (CB) {
      for (; i + 4 <= cn; i += 4) {
        float w0 = sS[(i + 0) * 8 + h], w1 = sS[(i + 1) * 8 + h];
        float w2 = sS[(i + 2) * 8 + h], w3 = sS[(i + 3) * 8 + h];
        int s0 = srcL[i], s1 = srcL[i + 1], s2 = srcL[i + 2], s3 = srcL[i + 3];
        int f0 = eL[i], f1 = eL[i + 1], f2 = eL[i + 2], f3 = eL[i + 3];
        ssum += w0 + w1 + w2 + w3;
        vo = fmaf(w0, b2f(QKVb[(size_t)s0 * 768 + 512 + t]), vo);
        vo = fmaf(w1, b2f(QKVb[(size_t)s1 * 768 + 512 + t]), vo);
        vo = fmaf(w2, b2f(QKVb[(size_t)s2 * 768 + 512 + t]), vo);
        vo = fmaf(w3, b2f(QKVb[(size_t)s3 * 768 + 512 + t]), vo);
        ro = fmaf(w0, b2f(connb[(size_t)f0 * 256 + t]), ro);
        ro = fmaf(w1, b2f(connb[(size_t)f1 * 256 + t]), ro);
        ro = fmaf(w2, b2f(connb[(size_t)f2 * 256 + t]), ro);
        ro = fmaf(w3, b2f(connb[(size_t)f3 * 256 + t]), ro);
      }
      for (; i < cn; i++) {
        float w0 = sS[i * 8 + h];
        ssum += w0;
        vo = fmaf(w0, b2f(QKVb[(size_t)srcL[i] * 768 + 512 + t]), vo);
        ro = fmaf(w0, b2f(connb[(size_t)eL[i] * 256 + t]), ro);
      }
    } else {
      for (; i + 4 <= cn; i += 4) {
        float w0 = sS[(i + 0) * 8 + h], w1 = sS[(i + 1) * 8 + h];
        float w2 = sS[(i + 2) * 8 + h], w3 = sS[(i + 3) * 8 + h];
        int s0 = srcL[i], s1 = srcL[i + 1], s2 = srcL[i + 2], s3 = srcL[i + 3];
        int f0 = eL[i], f1 = eL[i + 1], f2 = eL[i + 2], f3 = eL[i + 3];
        ssum += w0 + w1 + w2 + w3;
        vo = fmaf(w0, QKVh[(size_t)s0 * 768 + 512 + t], vo);
        vo = fmaf(w1, QKVh[(size_t)s1 * 768 + 512 + t], vo);
        vo = fmaf(w2, QKVh[(size_t)s2 * 768 + 512 + t], vo);
        vo = fmaf(w3, QKVh[(size_t)s3 * 768 + 512 + t], vo);
        ro = fmaf(w0, connf[(size_t)f0 * 256 + t], ro);
        ro = fmaf(w1, connf[(size_t)f1 * 256 + t], ro);
        ro = fmaf(w2, connf[(size_t)f2 * 256 + t], ro);
        ro = fmaf(w3, connf[(size_t)f3 * 256 + t], ro);
      }
      for (; i < cn; i++) {
        float w0 = sS[i * 8 + h];
        ssum += w0;
        vo = fmaf(w0, QKVh[(size_t)srcL[i] * 768 + 512 + t], vo);
        ro = fmaf(w0, connf[(size_t)eL[i] * 256 + t], ro);
      }
    }
  }
  const float inv = 1.f / (ssum + 1e-16f);
  vo *= inv;
  ro *= inv;
  __syncthreads();
  rA[t] = ro;
  __syncthreads();
  float acc = 0.f;
#pragma unroll
  for (int d = 0; d < 32; d++) acc = fmaf(rA[h * 32 + d], VeRow[d * 256 + t], acc);
  float v = QKVh[(size_t)n * 768 + t] + vo + acc;
  const float ld = log_deg[n];
  v = v * (deg_coef[2 * t] + ld * deg_coef[2 * t + 1]);
  nh_a[(size_t)n * 256 + t] = v;
}

// eh GEMM v3 (CB path): A fragments direct from connb into registers;
// B double-buffered in LDS -> 1 barrier per k-step. Fused bn1e stats.
__global__ __launch_bounds__(256) void eh_gemm2_k(
    const unsigned short* __restrict__ EowT, const float* __restrict__ Eob,
    const float* __restrict__ EA, const unsigned short* __restrict__ connb,
    float* __restrict__ eh, float* __restrict__ stb)
{
  __shared__ unsigned short Bl[2][256][40];
  __shared__ float lsum[256], lsq[256];
  const int t = threadIdx.x;
  const int e0 = blockIdx.x * 64;
  const int lane = t & 63, c = lane & 15, g = lane >> 4, w = t >> 6;
  lsum[t] = 0.f; lsq[t] = 0.f;
  bf16x8 areg[8];
  {
    const unsigned short* ap = connb + (size_t)(e0 + w * 16 + c) * 256 + g * 8;
#pragma unroll
    for (int ks = 0; ks < 8; ks++) areg[ks] = *(const bf16x8*)(ap + ks * 32);
  }
#pragma unroll
  for (int it = 0; it < 4; it++) {
    int o = t + it * 256;
    int row = o >> 2, kk = (o & 3) * 8;
    *(bf16x8*)&Bl[0][row][kk] = *(const bf16x8*)(EowT + (size_t)row * 256 + kk);
  }
  __syncthreads();
  f32x4 acc[16] = {};
  for (int ks = 0; ks < 8; ks++) {
    const int cur = ks & 1;
    if (ks + 1 < 8) {
#pragma unroll
      for (int it = 0; it < 4; it++) {
        int o = t + it * 256;
        int row = o >> 2, kk = (o & 3) * 8;
        *(bf16x8*)&Bl[cur ^ 1][row][kk] =
            *(const bf16x8*)(EowT + (size_t)row * 256 + (ks + 1) * 32 + kk);
      }
    }
    bf16x8 a = areg[ks];
#pragma unroll
    for (int nb = 0; nb < 16; nb++) {
      bf16x8 b = *(bf16x8*)&Bl[cur][nb * 16 + c][g * 8];
      acc[nb] = __builtin_amdgcn_mfma_f32_16x16x32_bf16(a, b, acc[nb], 0, 0, 0);
    }
    __syncthreads();   // stage(next) visible AND all reads of cur done
  }
#pragma unroll
  for (int nb = 0; nb < 16; nb++) {
    const int col = nb * 16 + c;
    const float eob = Eob[col];
    float sn = 0.f, qn = 0.f;
#pragma unroll
    for (int r = 0; r < 4; r++) {
      size_t row = e0 + w * 16 + g * 4 + r;
      float v = acc[nb][r] + eob + EA[row * 256 + col];
      eh[row * 256 + col] = v;
      sn += v; qn += v * v;
    }
    sn += __shfl_xor(sn, 16); sn += __shfl_xor(sn, 32);
    qn += __shfl_xor(qn, 16); qn += __shfl_xor(qn, 32);
    if (g == 0) { atomicAdd(&lsum[col], sn); atomicAdd(&lsq[col], qn); }
  }
  __syncthreads();
  float* dstb = stb + (size_t)(blockIdx.x & 63) * 512;
  atomicAdd(&dstb[t], lsum[t]);
  atomicAdd(&dstb[256 + t], lsq[t]);
}

// Fallback (f32 conn in-place in eh) — round-7 kernel, CB=0 semantics.
__global__ __launch_bounds__(256) void eh_gemm_k(
    const unsigned short* __restrict__ EowT, const float* __restrict__ Eob,
    const float* __restrict__ EA, float* __restrict__ eh, float* __restrict__ stb)
{
  __shared__ unsigned short Al[64][264];
  __shared__ unsigned short Bl[256][40];
  __shared__ float lsum[256], lsq[256];
  const int t = threadIdx.x;
  const int e0 = blockIdx.x * 64;
  const int lane = t & 63, c = lane & 15, g = lane >> 4, w = t >> 6;
  lsum[t] = 0.f; lsq[t] = 0.f;
#pragma unroll
  for (int it = 0; it < 8; it++) {
    int o = t + it * 256;
    int row = o >> 5, kk = (o & 31) * 8;
    const f4* p = (const f4*)(eh + (size_t)(e0 + row) * 256 + kk);
    f4 v0 = p[0], v1 = p[1];
    *(bf16x8*)&Al[row][kk] = pack8(v0, v1);
  }
  f32x4 acc[16] = {};
  for (int ks = 0; ks < 8; ks++) {
    __syncthreads();
#pragma unroll
    for (int it = 0; it < 4; it++) {
      int o = t + it * 256;
      int row = o >> 2, kk = (o & 3) * 8;
      *(bf16x8*)&Bl[row][kk] = *(const bf16x8*)(EowT + (size_t)row * 256 + ks * 32 + kk);
    }
    __syncthreads();
    bf16x8 a = *(bf16x8*)&Al[w * 16 + c][ks * 32 + g * 8];
#pragma unroll
    for (int nb = 0; nb < 16; nb++) {
      bf16x8 b = *(bf16x8*)&Bl[nb * 16 + c][g * 8];
      acc[nb] = __builtin_amdgcn_mfma_f32_16x16x32_bf16(a, b, acc[nb], 0, 0, 0);
    }
  }
#pragma unroll
  for (int nb = 0; nb < 16; nb++) {
    const int col = nb * 16 + c;
    const float eob = Eob[col];
    float sn = 0.f, qn = 0.f;
#pragma unroll
    for (int r = 0; r < 4; r++) {
      size_t row = e0 + w * 16 + g * 4 + r;
      float v = acc[nb][r] + eob + EA[row * 256 + col];
      eh[row * 256 + col] = v;
      sn += v; qn += v * v;
    }
    sn += __shfl_xor(sn, 16); sn += __shfl_xor(sn, 32);
    qn += __shfl_xor(qn, 16); qn += __shfl_xor(qn, 32);
    if (g == 0) { atomicAdd(&lsum[col], sn); atomicAdd(&lsq[col], qn); }
  }
  __syncthreads();
  float* dstb = stb + (size_t)(blockIdx.x & 63) * 512;
  atomicAdd(&dstb[t], lsum[t]);
  atomicAdd(&dstb[256 + t], lsq[t]);
}

__global__ void bn_fin_k(float* __restrict__ st, float invR)
{
  int t = threadIdx.x;
  float mean = st[t] * invR;
  float var = st[256 + t] * invR - mean * mean;
  st[t] = mean;
  st[256 + t] = rsqrtf(var + 1e-5f);
}

__global__ void bn_fin_banked_k(const float* __restrict__ banks, float* __restrict__ st,
                                float invR)
{
  int t = threadIdx.x;
  float s = 0.f, q = 0.f;
  for (int b = 0; b < 64; b++) {
    s += banks[(size_t)b * 512 + t];
    q += banks[(size_t)b * 512 + 256 + t];
  }
  float mean = s * invR;
  float var = q * invR - mean * mean;
  st[t] = mean;
  st[256 + t] = rsqrtf(var + 1e-5f);
}

__global__ void bn_apply_k(const float* __restrict__ X, float* __restrict__ Y,
                           const float* __restrict__ st, const float* __restrict__ g,
                           const float* __restrict__ b, long nvec)
{
  long i = (long)blockIdx.x * 256 + threadIdx.x;
  if (i >= nvec) return;
  int base = (int)(i & 63) * 4;
  f4 x = *(const f4*)(X + i * 4);
  f4 mn = *(const f4*)(st + base);
  f4 rs = *(const f4*)(st + 256 + base);
  f4 gg = *(const f4*)(g + base);
  f4 bb = *(const f4*)(b + base);
  f4 y;
#pragma unroll
  for (int j = 0; j < 4; j++) y[j] = (x[j] - mn[j]) * rs[j] * gg[j] + bb[j];
  *(f4*)(Y + i * 4) = y;
}

extern "C" void kernel_launch(void* const* d_in, const int* in_sizes, int n_in,
                              void* d_out, int out_size, void* d_ws, size_t ws_size,
                              hipStream_t stream)
{
  (void)in_sizes; (void)n_in; (void)out_size;
  const float* x        = (const float*)d_in[0];
  const float* edge_attr= (const float*)d_in[1];
  const float* log_deg  = (const float*)d_in[2];
  const int*   ei       = (const int*)d_in[3];
  const float* Qw = (const float*)d_in[4];  const float* Qb = (const float*)d_in[5];
  const float* Kw = (const float*)d_in[6];  const float* Kb = (const float*)d_in[7];
  const float* Ew = (const float*)d_in[8];  const float* Eb = (const float*)d_in[9];
  const float* Vw = (const float*)d_in[10]; const float* Vb = (const float*)d_in[11];
  const float* Aw = (const float*)d_in[12]; const float* VeRow = (const float*)d_in[13];
  const float* deg_coef = (const float*)d_in[14];
  const float* Now = (const float*)d_in[15]; const float* Nob = (const float*)d_in[16];
  const float* Eow = (const float*)d_in[17]; const float* Eob = (const float*)d_in[18];
  const float* bn1n_g = (const float*)d_in[19]; const float* bn1n_b = (const float*)d_in[20];
  const float* bn1e_g = (const float*)d_in[21]; const float* bn1e_b = (const float*)d_in[22];
  const float* f1w = (const float*)d_in[23]; const float* f1b = (const float*)d_in[24];
  const float* f2w = (const float*)d_in[25]; const float* f2b = (const float*)d_in[26];
  const float* bn2_g = (const float*)d_in[27]; const float* bn2_b = (const float*)d_in[28];

  float* out_nh = (float*)d_out;
  float* out_eh = out_nh + (size_t)NN * 256;   // eh output (conn f32 fallback lives here)

  float* ws     = (float*)d_ws;
  float* QKVh   = ws;                          // NN*768 f32
  unsigned short* QKVb = (unsigned short*)(QKVh + (size_t)NN * 768);  // NN*768 bf16
  float* score  = (float*)(QKVb + (size_t)NN * 768);  // NE*8 = 2.56M
  float* nh_a   = score + 2560000;
  float* nh2    = nh_a + 2560000;
  float* ffn1   = nh2 + 2560000;               // 5.12M
  float* st1    = ffn1 + 5120000;
  float* st2    = st1 + 512;
  float* st3    = st2 + 512;
  float* stb    = st3 + 512;                   // 64*512
  float* biasQKV= stb + 64 * 512;              // 768
  unsigned short* QwT = (unsigned short*)(biasQKV + 768);
  unsigned short* KwT = QwT + 65536;
  unsigned short* VwT = KwT + 65536;
  unsigned short* NowT= VwT + 65536;
  unsigned short* EowT= NowT + 65536;
  unsigned short* EwT = EowT + 65536;          // 131072
  unsigned short* f1wT= EwT + 131072;          // 131072
  unsigned short* f2wT= f1wT + 131072;         // 131072
  int*   cnt    = (int*)(f2wT + 131072);
  int*   off    = cnt + NN;                    // NN+1
  int*   cur    = off + NN + 1;
  int*   elist  = cur + NN;                    // NE
  int*   src_s  = elist + NE;                  // NE
  unsigned short* connb = (unsigned short*)(src_s + NE);  // NE*256 bf16 (optional)
  size_t need = (size_t)((char*)(connb + (size_t)NE * 256) - (char*)d_ws);
  const int CB = (ws_size >= need) ? 1 : 0;    // bf16-conn path if ws large enough

  hipMemsetAsync(cnt, 0, (size_t)NN * 4, stream);
  hipMemsetAsync(cur, 0, (size_t)NN * 4, stream);
  hipMemsetAsync(st1, 0, (size_t)2 * 512 * 4, stream);
  hipMemsetAsync(stb, 0, (size_t)64 * 512 * 4, stream);

  dim3 blk(256);

  // weight transpose+cast, bias concat
  castw_k<<<dim3(256), blk, 0, stream>>>(Qw, QwT, 256, 8);
  castw_k<<<dim3(256), blk, 0, stream>>>(Kw, KwT, 256, 8);
  castw_k<<<dim3(256), blk, 0, stream>>>(Vw, VwT, 256, 8);
  castw_k<<<dim3(256), blk, 0, stream>>>(Now, NowT, 256, 8);
  castw_k<<<dim3(256), blk, 0, stream>>>(Eow, EowT, 256, 8);
  castw_k<<<dim3(512), blk, 0, stream>>>(Ew, EwT, 256, 9);
  castw_k<<<dim3(512), blk, 0, stream>>>(f1w, f1wT, 256, 9);
  castw_k<<<dim3(512), blk, 0, stream>>>(f2w, f2wT, 512, 8);
  cat3_k<<<dim3(1), blk, 0, stream>>>(Qb, Kb, Vb, biasQKV);

  // CSR build
  hist_k<<<dim3(NE / 256), blk, 0, stream>>>(ei, cnt);
  scan_k<<<dim3(1), blk, 0, stream>>>(cnt, off);
  scat_k<<<dim3(NE / 256), blk, 0, stream>>>(ei, off, cur, elist, src_s);

  // fused QKV projection -> QKVh [N][768], then bf16 mirror QKVb
  gemm_bf16_k<<<dim3(6, 157), blk, 0, stream>>>(x, QwT, biasQKV, nullptr, QKVh, nullptr,
                                                NN, 256, 768, 0);
  castb_k<<<dim3((NN * 96 + 255) / 256), blk, 0, stream>>>(QKVh, QKVb, (long)NN * 96);

  // edge conn + score (v8: 128 edges/block, halved staging+barriers per edge)
  edge_conn_k<<<dim3(NE / 128), blk, 0, stream>>>(edge_attr, EwT, Eb, QKVb, ei, Aw,
                                                  out_eh, connb, score, CB);

  // per-node segment softmax + aggregation (V gathers from bf16 mirror)
  node_agg_k<<<dim3(NN), blk, 0, stream>>>(off, elist, src_s, score, QKVh, QKVb,
                                           out_eh, connb, CB,
                                           VeRow, deg_coef, log_deg, nh_a);

  // eh = conn @ Eow + Eob + edge_attr (+ fused bn1e stats)
  if (CB) {
    eh_gemm2_k<<<dim3(NE / 64), blk, 0, stream>>>(EowT, Eob, edge_attr, connb,
                                                  out_eh, stb);
  } else {
    eh_gemm_k<<<dim3(NE / 64), blk, 0, stream>>>(EowT, Eob, edge_attr, out_eh, stb);
  }
  bn_fin_banked_k<<<dim3(1), blk, 0, stream>>>(stb, st3, 1.0f / NE);
  bn_apply_k<<<dim3(NE * 64 / 256), blk, 0, stream>>>(out_eh, out_eh, st3,
                                                      bn1e_g, bn1e_b, (long)NE * 64);

  // node path: nh1 = nh_a @ Now + Nob + x (+bn1n stats)
  gemm_bf16_k<<<dim3(2, 157), blk, 0, stream>>>(nh_a, NowT, Nob, x, out_nh, st1,
                                                NN, 256, 256, 2);
  bn_fin_k<<<dim3(1), blk, 0, stream>>>(st1, 1.0f / NN);
  bn_apply_k<<<dim3(NN * 64 / 256), blk, 0, stream>>>(out_nh, nh2, st1,
                                                      bn1n_g, bn1n_b, (long)NN * 64);
  // FFN
  gemm_bf16_k<<<dim3(4, 157), blk, 0, stream>>>(nh2, f1wT, f1b, nullptr, ffn1, nullptr,
                                                NN, 256, 512, 1);
  gemm_bf16_k<<<dim3(2, 157), blk, 0, stream>>>(ffn1, f2wT, f2b, nh2, out_nh, st2,
                                                NN, 512, 256, 2);
  bn_fin_k<<<dim3(1), blk, 0, stream>>>(st2, 1.0f / NN);
  bn_apply_k<<<dim3(NN * 64 / 256), blk, 0, stream>>>(out_nh, out_nh, st2,
                                                      bn2_g, bn2_b, (long)NN * 64);
}

// Round 16
// 933.870 us; speedup vs baseline: 1.1702x; 1.1702x over previous
//
#include <hip/hip_runtime.h>

#define NN 10000
#define NE 320000

typedef float f4 __attribute__((ext_vector_type(4)));
typedef float f32x4 __attribute__((ext_vector_type(4)));
typedef short bf16x8 __attribute__((ext_vector_type(8)));

__device__ __forceinline__ unsigned short f2b(float f) {
  unsigned u = __float_as_uint(f);
  u += 0x7fff + ((u >> 16) & 1);          // RNE
  return (unsigned short)(u >> 16);
}
__device__ __forceinline__ float b2f(unsigned short s) {
  return __uint_as_float(((unsigned)s) << 16);
}
__device__ __forceinline__ bf16x8 pack8(f4 a, f4 b) {
  bf16x8 r;
  r[0] = (short)f2b(a[0]); r[1] = (short)f2b(a[1]);
  r[2] = (short)f2b(a[2]); r[3] = (short)f2b(a[3]);
  r[4] = (short)f2b(b[0]); r[5] = (short)f2b(b[1]);
  r[6] = (short)f2b(b[2]); r[7] = (short)f2b(b[3]);
  return r;
}
// swizzled ushort index into a flat [64][256] bf16 tile (XOR bank swizzle)
__device__ __forceinline__ int swz(int row, int k) {
  return (row * 256) + (k ^ ((row & 7) << 3));
}

// transpose+cast weights: in f32 [K][N] -> out bf16 [N][K]
__global__ void castw_k(const float* __restrict__ in, unsigned short* __restrict__ out,
                        int K, int lg)
{
  int idx = blockIdx.x * 256 + threadIdx.x;
  if (idx >= (K << lg)) return;
  int n = idx & ((1 << lg) - 1), k = idx >> lg;
  out[(size_t)n * K + k] = f2b(in[idx]);
}

// contiguous f32 -> bf16 cast (8 elems/thread)
__global__ void castb_k(const float* __restrict__ in, unsigned short* __restrict__ out,
                        long n8)
{
  long i = (long)blockIdx.x * 256 + threadIdx.x;
  if (i >= n8) return;
  const f4* p = (const f4*)(in + i * 8);
  *(bf16x8*)(out + i * 8) = pack8(p[0], p[1]);
}

__global__ void cat3_k(const float* __restrict__ a, const float* __restrict__ b,
                       const float* __restrict__ c, float* __restrict__ o)
{
  int t = threadIdx.x;
  o[t] = a[t]; o[256 + t] = b[t]; o[512 + t] = c[t];
}

// Generic node-side MFMA GEMM: C[M,N] = act(castbf16(A[M,K]) @ BT^T + bias (+res))
__global__ __launch_bounds__(256) void gemm_bf16_k(
    const float* __restrict__ A, const unsigned short* __restrict__ BT,
    const float* __restrict__ bias, const float* __restrict__ res,
    float* __restrict__ C, float* __restrict__ stats,
    int M, int K, int NT, int flags)
{
  __shared__ unsigned short Al[64][40];
  __shared__ unsigned short Bl[128][40];
  const int t = threadIdx.x;
  const int n0 = blockIdx.x * 128;
  const int m0 = blockIdx.y * 64;
  const int lane = t & 63, c = lane & 15, g = lane >> 4, w = t >> 6;
  f32x4 acc[8] = {};
  for (int k0 = 0; k0 < K; k0 += 32) {
    {
      int row = t >> 2, kk = (t & 3) * 8;
      f4 v0 = {0.f,0.f,0.f,0.f}, v1 = {0.f,0.f,0.f,0.f};
      if (m0 + row < M) {
        const f4* p = (const f4*)(A + (size_t)(m0 + row) * K + k0 + kk);
        v0 = p[0]; v1 = p[1];
      }
      __syncthreads();
      *(bf16x8*)&Al[row][kk] = pack8(v0, v1);
    }
    {
      int col = t >> 1, kk = (t & 1) * 16;
      const bf16x8* p = (const bf16x8*)(BT + (size_t)(n0 + col) * K + k0 + kk);
      *(bf16x8*)&Bl[col][kk] = p[0];
      *(bf16x8*)&Bl[col][kk + 8] = p[1];
    }
    __syncthreads();
    bf16x8 a = *(bf16x8*)&Al[w * 16 + c][g * 8];
#pragma unroll
    for (int nb = 0; nb < 8; nb++) {
      bf16x8 b = *(bf16x8*)&Bl[nb * 16 + c][g * 8];
      acc[nb] = __builtin_amdgcn_mfma_f32_16x16x32_bf16(a, b, acc[nb], 0, 0, 0);
    }
  }
  const int do_relu = flags & 1, do_stats = flags & 2;
#pragma unroll
  for (int nb = 0; nb < 8; nb++) {
    const int col = n0 + nb * 16 + c;
    const float bs = bias[col];
    float sn = 0.f, qn = 0.f;
#pragma unroll
    for (int r = 0; r < 4; r++) {
      int row = m0 + w * 16 + g * 4 + r;
      if (row < M) {
        float v = acc[nb][r] + bs;
        if (res) v += res[(size_t)row * NT + col];
        if (do_relu) v = fmaxf(v, 0.f);
        C[(size_t)row * NT + col] = v;
        sn += v; qn += v * v;
      }
    }
    if (do_stats) {
      sn += __shfl_xor(sn, 16); sn += __shfl_xor(sn, 32);
      qn += __shfl_xor(qn, 16); qn += __shfl_xor(qn, 32);
      if (g == 0) {
        atomicAdd(&stats[col], sn);
        atomicAdd(&stats[NT + col], qn);
      }
    }
  }
}

// Edge kernel v6 (round-11/14 proven): A bounced LDS->registers, 32KB buffer
// reused as per-head B tile; 9KB padded bf16 ExlB; 41KB LDS -> 3 blocks/CU.
__global__ __launch_bounds__(256, 3) void edge_conn_k(
    const float* __restrict__ EA, const unsigned short* __restrict__ EwT,
    const float* __restrict__ Eb, const unsigned short* __restrict__ QKVb,
    const int* __restrict__ ei, const float* __restrict__ Aw,
    float* __restrict__ connf, unsigned short* __restrict__ connb,
    float* __restrict__ score, int CB)
{
  __shared__ unsigned short sh[16384];     // 32KB: A staging, then B per head
  __shared__ unsigned short ExlB[64 * 72]; // 9KB bf16 transpose buffer
  const int t = threadIdx.x;
  const int e0 = blockIdx.x * 64;
  const int lane = t & 63, c = lane & 15, g = lane >> 4, w = t >> 6;
  // 1) stage EA coalesced (full-line streams) as bf16, swizzled [64][256]
#pragma unroll
  for (int it = 0; it < 8; it++) {
    int o = t + it * 256;
    int row = o >> 5, kk = (o & 31) * 8;
    const f4* p = (const f4*)(EA + (size_t)(e0 + row) * 256 + kk);
    f4 v0 = p[0], v1 = p[1];
    *(bf16x8*)&sh[swz(row, kk)] = pack8(v0, v1);
  }
  const int m2 = t >> 2, dg = t & 3;
  const int e = e0 + m2;
  const int src = ei[e], dst = ei[NE + e];
  const unsigned short* kbase = QKVb + (size_t)src * 768 + 256 + dg * 8;
  const unsigned short* qbase = QKVb + (size_t)dst * 768 + dg * 8;
  __syncthreads();   // A staged
  // 2) A fragments LDS -> registers (conflict-free under swz)
  bf16x8 areg[8];
#pragma unroll
  for (int i = 0; i < 8; i++)
    areg[i] = *(bf16x8*)&sh[swz(w * 16 + c, i * 32 + g * 8)];
  __syncthreads();   // all A reads done; sh reusable for B

  for (int h = 0; h < 8; h++) {
    // prefetch K/Q for this head (consumed after MFMA)
    bf16x8 kv8 = *(const bf16x8*)(kbase + h * 32);
    bf16x8 qv8 = *(const bf16x8*)(qbase + h * 32);
    // stage B (EwT rows for head h) into sh
#pragma unroll
    for (int it = 0; it < 8; it++) {
      int o = t + it * 256;
      int row = o >> 5, kk = (o & 31) * 8;
      *(bf16x8*)&sh[swz(row, kk)] =
          *(const bf16x8*)(EwT + (size_t)(h * 64 + row) * 256 + kk);
    }
    __syncthreads();   // B ready
    f32x4 acc[4] = {};
#pragma unroll
    for (int ks = 0; ks < 8; ks++) {
      bf16x8 a = areg[ks];
#pragma unroll
      for (int cb = 0; cb < 4; cb++) {
        bf16x8 b = *(bf16x8*)&sh[swz(cb * 16 + c, ks * 32 + g * 8)];
        acc[cb] = __builtin_amdgcn_mfma_f32_16x16x32_bf16(a, b, acc[cb], 0, 0, 0);
      }
    }
    // write Ex (bf16) into ExlB -- intra-wave communication, no barrier
#pragma unroll
    for (int cb = 0; cb < 4; cb++) {
      float eb = Eb[h * 64 + cb * 16 + c];
#pragma unroll
      for (int r = 0; r < 4; r++)
        ExlB[(w * 16 + g * 4 + r) * 72 + cb * 16 + c] = f2b(acc[cb][r] + eb);
    }
    // epilogue: conn + score for head h (reads ExlB row m2 -- same wave wrote it)
    {
      bf16x8 x1 = *(bf16x8*)&ExlB[m2 * 72 + dg * 8];
      bf16x8 x2 = *(bf16x8*)&ExlB[m2 * 72 + 32 + dg * 8];
      const int cb2 = h * 32 + dg * 8;
      f4 c1, c2;
      float part = 0.f;
#pragma unroll
      for (int j = 0; j < 4; j++) {
        float ex1 = b2f((unsigned short)x1[j]);
        float ex2 = b2f((unsigned short)x2[j]);
        float s2 = ex1 * ex2;
        float v = copysignf(sqrtf(fabsf(s2)), s2)
                + b2f((unsigned short)kv8[j]) + b2f((unsigned short)qv8[j]);
        v = fmaxf(v, 0.f);
        c1[j] = v;
        part += v * Aw[(dg * 8 + j) * 8 + h];
        float ex1b = b2f((unsigned short)x1[j + 4]);
        float ex2b = b2f((unsigned short)x2[j + 4]);
        float s2b = ex1b * ex2b;
        float vb = copysignf(sqrtf(fabsf(s2b)), s2b)
                 + b2f((unsigned short)kv8[j + 4]) + b2f((unsigned short)qv8[j + 4]);
        vb = fmaxf(vb, 0.f);
        c2[j] = vb;
        part += vb * Aw[(dg * 8 + 4 + j) * 8 + h];
      }
      if (CB) {
        *(bf16x8*)(connb + (size_t)e * 256 + cb2) = pack8(c1, c2);  // 16B store
      } else {
        *(f4*)(connf + (size_t)e * 256 + cb2) = c1;
        *(f4*)(connf + (size_t)e * 256 + cb2 + 4) = c2;
      }
      part += __shfl_xor(part, 1);
      part += __shfl_xor(part, 2);
      if (dg == 0) score[(size_t)e * 8 + h] = fminf(fmaxf(part, -5.f), 5.f);
    }
    __syncthreads();   // all MFMA reads of sh done before next head's restage
  }
}

// ---------- CSR build (by destination) ----------
__global__ void hist_k(const int* __restrict__ ei, int* __restrict__ cnt)
{
  int e = blockIdx.x * 256 + threadIdx.x;
  if (e < NE) atomicAdd(&cnt[ei[NE + e]], 1);
}

__global__ __launch_bounds__(256) void scan_k(const int* __restrict__ cnt, int* __restrict__ off)
{
  __shared__ int part[256];
  const int t = threadIdx.x;
  const int PER = 40;
  const int base = t * PER;
  int s = 0;
  for (int i = 0; i < PER; i++) {
    int b = base + i;
    if (b < NN) s += cnt[b];
  }
  part[t] = s;
  __syncthreads();
  for (int d = 1; d < 256; d <<= 1) {
    int v = (t >= d) ? part[t - d] : 0;
    __syncthreads();
    part[t] += v;
    __syncthreads();
  }
  int run = (t == 0) ? 0 : part[t - 1];
  for (int i = 0; i < PER; i++) {
    int b = base + i;
    if (b < NN) { off[b] = run; run += cnt[b]; }
  }
  if (t == 255) off[NN] = run;
}

__global__ void scat_k(const int* __restrict__ ei, const int* __restrict__ off,
                       int* __restrict__ cur, int* __restrict__ elist,
                       int* __restrict__ src_s)
{
  int e = blockIdx.x * 256 + threadIdx.x;
  if (e < NE) {
    int s = ei[e], d = ei[NE + e];
    int p = atomicAdd(&cur[d], 1);
    int j = off[d] + p;
    elist[j] = e;
    src_s[j] = s;
  }
}

// One block per node: online segment softmax (parallel max/exp) + weighted
// aggregation + rowV einsum + degree scaler. V gathered from bf16 mirror.
__global__ __launch_bounds__(256) void node_agg_k(
    const int* __restrict__ off, const int* __restrict__ elist,
    const int* __restrict__ src_s, const float* __restrict__ score,
    const float* __restrict__ QKVh, const unsigned short* __restrict__ QKVb,
    const float* __restrict__ connf, const unsigned short* __restrict__ connb, int CB,
    const float* __restrict__ VeRow, const float* __restrict__ deg_coef,
    const float* __restrict__ log_deg, float* __restrict__ nh_a)
{
  const int n = blockIdx.x, t = threadIdx.x;
  const int h = t >> 5;
  __shared__ int eL[128];
  __shared__ int srcL[128];
  __shared__ float sS[1024];
  __shared__ float mS[8];
  __shared__ float rA[256];
  const int start = off[n];
  const int deg = off[n + 1] - start;
  float m = -1e30f, ssum = 0.f, vo = 0.f, ro = 0.f;
  for (int c0 = 0; c0 < deg; c0 += 128) {
    const int cn = min(128, deg - c0);
    __syncthreads();
    if (t < cn) {
      int jj = start + c0 + t;
      eL[t] = elist[jj];
      srcL[t] = src_s[jj];
    }
    __syncthreads();
    for (int i = t; i < cn * 8; i += 256) sS[i] = score[(size_t)eL[i >> 3] * 8 + (i & 7)];
    __syncthreads();
    float mc = -1e30f;
    for (int i = (t & 31); i < cn; i += 32) mc = fmaxf(mc, sS[i * 8 + h]);
    mc = fmaxf(mc, __shfl_xor(mc, 1));
    mc = fmaxf(mc, __shfl_xor(mc, 2));
    mc = fmaxf(mc, __shfl_xor(mc, 4));
    mc = fmaxf(mc, __shfl_xor(mc, 8));
    mc = fmaxf(mc, __shfl_xor(mc, 16));
    float nm = fmaxf(m, mc);
    if ((t & 31) == 0) mS[h] = nm;
    __syncthreads();
    for (int i = t; i < cn * 8; i += 256) sS[i] = __expf(sS[i] - mS[i & 7]);
    __syncthreads();
    float sc = __expf(m - nm);
    ssum *= sc; vo *= sc; ro *= sc;
    m = nm;
    int i = 0;
    if (CB) {
      for (; i + 4 <= cn; i += 4) {
        float w0 = sS[(i + 0) * 8 + h], w1 = sS[(i + 1) * 8 + h];
        float w2 = sS[(i + 2) * 8 + h], w3 = sS[(i + 3) * 8 + h];
        int s0 = srcL[i], s1 = srcL[i + 1], s2 = srcL[i + 2], s3 = srcL[i + 3];
        int f0 = eL[i], f1 = eL[i + 1], f2 = eL[i + 2], f3 = eL[i + 3];
        ssum += w0 + w1 + w2 + w3;
        vo = fmaf(w0, b2f(QKVb[(size_t)s0 * 768 + 512 + t]), vo);
        vo = fmaf(w1, b2f(QKVb[(size_t)s1 * 768 + 512 + t]), vo);
        vo = fmaf(w2, b2f(QKVb[(size_t)s2 * 768 + 512 + t]), vo);
        vo = fmaf(w3, b2f(QKVb[(size_t)s3 * 768 + 512 + t]), vo);
        ro = fmaf(w0, b2f(connb[(size_t)f0 * 256 + t]), ro);
        ro = fmaf(w1, b2f(connb[(size_t)f1 * 256 + t]), ro);
        ro = fmaf(w2, b2f(connb[(size_t)f2 * 256 + t]), ro);
        ro = fmaf(w3, b2f(connb[(size_t)f3 * 256 + t]), ro);
      }
      for (; i < cn; i++) {
        float w0 = sS[i * 8 + h];
        ssum += w0;
        vo = fmaf(w0, b2f(QKVb[(size_t)srcL[i] * 768 + 512 + t]), vo);
        ro = fmaf(w0, b2f(connb[(size_t)eL[i] * 256 + t]), ro);
      }
    } else {
      for (; i + 4 <= cn; i += 4) {
        float w0 = sS[(i + 0) * 8 + h], w1 = sS[(i + 1) * 8 + h];
        float w2 = sS[(i + 2) * 8 + h], w3 = sS[(i + 3) * 8 + h];
        int s0 = srcL[i], s1 = srcL[i + 1], s2 = srcL[i + 2], s3 = srcL[i + 3];
        int f0 = eL[i], f1 = eL[i + 1], f2 = eL[i + 2], f3 = eL[i + 3];
        ssum += w0 + w1 + w2 + w3;
        vo = fmaf(w0, QKVh[(size_t)s0 * 768 + 512 + t], vo);
        vo = fmaf(w1, QKVh[(size_t)s1 * 768 + 512 + t], vo);
        vo = fmaf(w2, QKVh[(size_t)s2 * 768 + 512 + t], vo);
        vo = fmaf(w3, QKVh[(size_t)s3 * 768 + 512 + t], vo);
        ro = fmaf(w0, connf[(size_t)f0 * 256 + t], ro);
        ro = fmaf(w1, connf[(size_t)f1 * 256 + t], ro);
        ro = fmaf(w2, connf[(size_t)f2 * 256 + t], ro);
        ro = fmaf(w3, connf[(size_t)f3 * 256 + t], ro);
      }
      for (; i < cn; i++) {
        float w0 = sS[i * 8 + h];
        ssum += w0;
        vo = fmaf(w0, QKVh[(size_t)srcL[i] * 768 + 512 + t], vo);
        ro = fmaf(w0, connf[(size_t)eL[i] * 256 + t], ro);
      }
    }
  }
  const float inv = 1.f / (ssum + 1e-16f);
  vo *= inv;
  ro *= inv;
  __syncthreads();
  rA[t] = ro;
  __syncthreads();
  float acc = 0.f;
#pragma unroll
  for (int d = 0; d < 32; d++) acc = fmaf(rA[h * 32 + d], VeRow[d * 256 + t], acc);
  float v = QKVh[(size_t)n * 768 + t] + vo + acc;
  const float ld = log_deg[n];
  v = v * (deg_coef[2 * t] + ld * deg_coef[2 * t + 1]);
  nh_a[(size_t)n * 256 + t] = v;
}

// eh GEMM v3 (CB path): A fragments direct from connb into registers;
// B double-buffered in LDS -> 1 barrier per k-step. Fused bn1e stats.
__global__ __launch_bounds__(256) void eh_gemm2_k(
    const unsigned short* __restrict__ EowT, const float* __restrict__ Eob,
    const float* __restrict__ EA, const unsigned short* __restrict__ connb,
    float* __restrict__ eh, float* __restrict__ stb)
{
  __shared__ unsigned short Bl[2][256][40];
  __shared__ float lsum[256], lsq[256];
  const int t = threadIdx.x;
  const int e0 = blockIdx.x * 64;
  const int lane = t & 63, c = lane & 15, g = lane >> 4, w = t >> 6;
  lsum[t] = 0.f; lsq[t] = 0.f;
  bf16x8 areg[8];
  {
    const unsigned short* ap = connb + (size_t)(e0 + w * 16 + c) * 256 + g * 8;
#pragma unroll
    for (int ks = 0; ks < 8; ks++) areg[ks] = *(const bf16x8*)(ap + ks * 32);
  }
#pragma unroll
  for (int it = 0; it < 4; it++) {
    int o = t + it * 256;
    int row = o >> 2, kk = (o & 3) * 8;
    *(bf16x8*)&Bl[0][row][kk] = *(const bf16x8*)(EowT + (size_t)row * 256 + kk);
  }
  __syncthreads();
  f32x4 acc[16] = {};
  for (int ks = 0; ks < 8; ks++) {
    const int cur = ks & 1;
    if (ks + 1 < 8) {
#pragma unroll
      for (int it = 0; it < 4; it++) {
        int o = t + it * 256;
        int row = o >> 2, kk = (o & 3) * 8;
        *(bf16x8*)&Bl[cur ^ 1][row][kk] =
            *(const bf16x8*)(EowT + (size_t)row * 256 + (ks + 1) * 32 + kk);
      }
    }
    bf16x8 a = areg[ks];
#pragma unroll
    for (int nb = 0; nb < 16; nb++) {
      bf16x8 b = *(bf16x8*)&Bl[cur][nb * 16 + c][g * 8];
      acc[nb] = __builtin_amdgcn_mfma_f32_16x16x32_bf16(a, b, acc[nb], 0, 0, 0);
    }
    __syncthreads();   // stage(next) visible AND all reads of cur done
  }
#pragma unroll
  for (int nb = 0; nb < 16; nb++) {
    const int col = nb * 16 + c;
    const float eob = Eob[col];
    float sn = 0.f, qn = 0.f;
#pragma unroll
    for (int r = 0; r < 4; r++) {
      size_t row = e0 + w * 16 + g * 4 + r;
      float v = acc[nb][r] + eob + EA[row * 256 + col];
      eh[row * 256 + col] = v;
      sn += v; qn += v * v;
    }
    sn += __shfl_xor(sn, 16); sn += __shfl_xor(sn, 32);
    qn += __shfl_xor(qn, 16); qn += __shfl_xor(qn, 32);
    if (g == 0) { atomicAdd(&lsum[col], sn); atomicAdd(&lsq[col], qn); }
  }
  __syncthreads();
  float* dstb = stb + (size_t)(blockIdx.x & 63) * 512;
  atomicAdd(&dstb[t], lsum[t]);
  atomicAdd(&dstb[256 + t], lsq[t]);
}

// Fallback (f32 conn in-place in eh) — round-7 kernel, CB=0 semantics.
__global__ __launch_bounds__(256) void eh_gemm_k(
    const unsigned short* __restrict__ EowT, const float* __restrict__ Eob,
    const float* __restrict__ EA, float* __restrict__ eh, float* __restrict__ stb)
{
  __shared__ unsigned short Al[64][264];
  __shared__ unsigned short Bl[256][40];
  __shared__ float lsum[256], lsq[256];
  const int t = threadIdx.x;
  const int e0 = blockIdx.x * 64;
  const int lane = t & 63, c = lane & 15, g = lane >> 4, w = t >> 6;
  lsum[t] = 0.f; lsq[t] = 0.f;
#pragma unroll
  for (int it = 0; it < 8; it++) {
    int o = t + it * 256;
    int row = o >> 5, kk = (o & 31) * 8;
    const f4* p = (const f4*)(eh + (size_t)(e0 + row) * 256 + kk);
    f4 v0 = p[0], v1 = p[1];
    *(bf16x8*)&Al[row][kk] = pack8(v0, v1);
  }
  f32x4 acc[16] = {};
  for (int ks = 0; ks < 8; ks++) {
    __syncthreads();
#pragma unroll
    for (int it = 0; it < 4; it++) {
      int o = t + it * 256;
      int row = o >> 2, kk = (o & 3) * 8;
      *(bf16x8*)&Bl[row][kk] = *(const bf16x8*)(EowT + (size_t)row * 256 + ks * 32 + kk);
    }
    __syncthreads();
    bf16x8 a = *(bf16x8*)&Al[w * 16 + c][ks * 32 + g * 8];
#pragma unroll
    for (int nb = 0; nb < 16; nb++) {
      bf16x8 b = *(bf16x8*)&Bl[nb * 16 + c][g * 8];
      acc[nb] = __builtin_amdgcn_mfma_f32_16x16x32_bf16(a, b, acc[nb], 0, 0, 0);
    }
  }
#pragma unroll
  for (int nb = 0; nb < 16; nb++) {
    const int col = nb * 16 + c;
    const float eob = Eob[col];
    float sn = 0.f, qn = 0.f;
#pragma unroll
    for (int r = 0; r < 4; r++) {
      size_t row = e0 + w * 16 + g * 4 + r;
      float v = acc[nb][r] + eob + EA[row * 256 + col];
      eh[row * 256 + col] = v;
      sn += v; qn += v * v;
    }
    sn += __shfl_xor(sn, 16); sn += __shfl_xor(sn, 32);
    qn += __shfl_xor(qn, 16); qn += __shfl_xor(qn, 32);
    if (g == 0) { atomicAdd(&lsum[col], sn); atomicAdd(&lsq[col], qn); }
  }
  __syncthreads();
  float* dstb = stb + (size_t)(blockIdx.x & 63) * 512;
  atomicAdd(&dstb[t], lsum[t]);
  atomicAdd(&dstb[256 + t], lsq[t]);
}

__global__ void bn_fin_k(float* __restrict__ st, float invR)
{
  int t = threadIdx.x;
  float mean = st[t] * invR;
  float var = st[256 + t] * invR - mean * mean;
  st[t] = mean;
  st[256 + t] = rsqrtf(var + 1e-5f);
}

__global__ void bn_fin_banked_k(const float* __restrict__ banks, float* __restrict__ st,
                                float invR)
{
  int t = threadIdx.x;
  float s = 0.f, q = 0.f;
  for (int b = 0; b < 64; b++) {
    s += banks[(size_t)b * 512 + t];
    q += banks[(size_t)b * 512 + 256 + t];
  }
  float mean = s * invR;
  float var = q * invR - mean * mean;
  st[t] = mean;
  st[256 + t] = rsqrtf(var + 1e-5f);
}

__global__ void bn_apply_k(const float* __restrict__ X, float* __restrict__ Y,
                           const float* __restrict__ st, const float* __restrict__ g,
                           const float* __restrict__ b, long nvec)
{
  long i = (long)blockIdx.x * 256 + threadIdx.x;
  if (i >= nvec) return;
  int base = (int)(i & 63) * 4;
  f4 x = *(const f4*)(X + i * 4);
  f4 mn = *(const f4*)(st + base);
  f4 rs = *(const f4*)(st + 256 + base);
  f4 gg = *(const f4*)(g + base);
  f4 bb = *(const f4*)(b + base);
  f4 y;
#pragma unroll
  for (int j = 0; j < 4; j++) y[j] = (x[j] - mn[j]) * rs[j] * gg[j] + bb[j];
  *(f4*)(Y + i * 4) = y;
}

extern "C" void kernel_launch(void* const* d_in, const int* in_sizes, int n_in,
                              void* d_out, int out_size, void* d_ws, size_t ws_size,
                              hipStream_t stream)
{
  (void)in_sizes; (void)n_in; (void)out_size;
  const float* x        = (const float*)d_in[0];
  const float* edge_attr= (const float*)d_in[1];
  const float* log_deg  = (const float*)d_in[2];
  const int*   ei       = (const int*)d_in[3];
  const float* Qw = (const float*)d_in[4];  const float* Qb = (const float*)d_in[5];
  const float* Kw = (const float*)d_in[6];  const float* Kb = (const float*)d_in[7];
  const float* Ew = (const float*)d_in[8];  const float* Eb = (const float*)d_in[9];
  const float* Vw = (const float*)d_in[10]; const float* Vb = (const float*)d_in[11];
  const float* Aw = (const float*)d_in[12]; const float* VeRow = (const float*)d_in[13];
  const float* deg_coef = (const float*)d_in[14];
  const float* Now = (const float*)d_in[15]; const float* Nob = (const float*)d_in[16];
  const float* Eow = (const float*)d_in[17]; const float* Eob = (const float*)d_in[18];
  const float* bn1n_g = (const float*)d_in[19]; const float* bn1n_b = (const float*)d_in[20];
  const float* bn1e_g = (const float*)d_in[21]; const float* bn1e_b = (const float*)d_in[22];
  const float* f1w = (const float*)d_in[23]; const float* f1b = (const float*)d_in[24];
  const float* f2w = (const float*)d_in[25]; const float* f2b = (const float*)d_in[26];
  const float* bn2_g = (const float*)d_in[27]; const float* bn2_b = (const float*)d_in[28];

  float* out_nh = (float*)d_out;
  float* out_eh = out_nh + (size_t)NN * 256;   // eh output (conn f32 fallback lives here)

  float* ws     = (float*)d_ws;
  float* QKVh   = ws;                          // NN*768 f32
  unsigned short* QKVb = (unsigned short*)(QKVh + (size_t)NN * 768);  // NN*768 bf16
  float* score  = (float*)(QKVb + (size_t)NN * 768);  // NE*8 = 2.56M
  float* nh_a   = score + 2560000;
  float* nh2    = nh_a + 2560000;
  float* ffn1   = nh2 + 2560000;               // 5.12M
  float* st1    = ffn1 + 5120000;
  float* st2    = st1 + 512;
  float* st3    = st2 + 512;
  float* stb    = st3 + 512;                   // 64*512
  float* biasQKV= stb + 64 * 512;              // 768
  unsigned short* QwT = (unsigned short*)(biasQKV + 768);
  unsigned short* KwT = QwT + 65536;
  unsigned short* VwT = KwT + 65536;
  unsigned short* NowT= VwT + 65536;
  unsigned short* EowT= NowT + 65536;
  unsigned short* EwT = EowT + 65536;          // 131072
  unsigned short* f1wT= EwT + 131072;          // 131072
  unsigned short* f2wT= f1wT + 131072;         // 131072
  int*   cnt    = (int*)(f2wT + 131072);
  int*   off    = cnt + NN;                    // NN+1
  int*   cur    = off + NN + 1;
  int*   elist  = cur + NN;                    // NE
  int*   src_s  = elist + NE;                  // NE
  unsigned short* connb = (unsigned short*)(src_s + NE);  // NE*256 bf16 (optional)
  size_t need = (size_t)((char*)(connb + (size_t)NE * 256) - (char*)d_ws);
  const int CB = (ws_size >= need) ? 1 : 0;    // bf16-conn path if ws large enough

  hipMemsetAsync(cnt, 0, (size_t)NN * 4, stream);
  hipMemsetAsync(cur, 0, (size_t)NN * 4, stream);
  hipMemsetAsync(st1, 0, (size_t)2 * 512 * 4, stream);
  hipMemsetAsync(stb, 0, (size_t)64 * 512 * 4, stream);

  dim3 blk(256);

  // weight transpose+cast, bias concat
  castw_k<<<dim3(256), blk, 0, stream>>>(Qw, QwT, 256, 8);
  castw_k<<<dim3(256), blk, 0, stream>>>(Kw, KwT, 256, 8);
  castw_k<<<dim3(256), blk, 0, stream>>>(Vw, VwT, 256, 8);
  castw_k<<<dim3(256), blk, 0, stream>>>(Now, NowT, 256, 8);
  castw_k<<<dim3(256), blk, 0, stream>>>(Eow, EowT, 256, 8);
  castw_k<<<dim3(512), blk, 0, stream>>>(Ew, EwT, 256, 9);
  castw_k<<<dim3(512), blk, 0, stream>>>(f1w, f1wT, 256, 9);
  castw_k<<<dim3(512), blk, 0, stream>>>(f2w, f2wT, 512, 8);
  cat3_k<<<dim3(1), blk, 0, stream>>>(Qb, Kb, Vb, biasQKV);

  // CSR build
  hist_k<<<dim3(NE / 256), blk, 0, stream>>>(ei, cnt);
  scan_k<<<dim3(1), blk, 0, stream>>>(cnt, off);
  scat_k<<<dim3(NE / 256), blk, 0, stream>>>(ei, off, cur, elist, src_s);

  // fused QKV projection -> QKVh [N][768], then bf16 mirror QKVb
  gemm_bf16_k<<<dim3(6, 157), blk, 0, stream>>>(x, QwT, biasQKV, nullptr, QKVh, nullptr,
                                                NN, 256, 768, 0);
  castb_k<<<dim3((NN * 96 + 255) / 256), blk, 0, stream>>>(QKVh, QKVb, (long)NN * 96);

  // edge conn + score (round-11/14 v6 proven structure)
  edge_conn_k<<<dim3(NE / 64), blk, 0, stream>>>(edge_attr, EwT, Eb, QKVb, ei, Aw,
                                                 out_eh, connb, score, CB);

  // per-node segment softmax + aggregation (V gathers from bf16 mirror)
  node_agg_k<<<dim3(NN), blk, 0, stream>>>(off, elist, src_s, score, QKVh, QKVb,
                                           out_eh, connb, CB,
                                           VeRow, deg_coef, log_deg, nh_a);

  // eh = conn @ Eow + Eob + edge_attr (+ fused bn1e stats)
  if (CB) {
    eh_gemm2_k<<<dim3(NE / 64), blk, 0, stream>>>(EowT, Eob, edge_attr, connb,
                                                  out_eh, stb);
  } else {
    eh_gemm_k<<<dim3(NE / 64), blk, 0, stream>>>(EowT, Eob, edge_attr, out_eh, stb);
  }
  bn_fin_banked_k<<<dim3(1), blk, 0, stream>>>(stb, st3, 1.0f / NE);
  bn_apply_k<<<dim3(NE * 64 / 256), blk, 0, stream>>>(out_eh, out_eh, st3,
                                                      bn1e_g, bn1e_b, (long)NE * 64);

  // node path: nh1 = nh_a @ Now + Nob + x (+bn1n stats)
  gemm_bf16_k<<<dim3(2, 157), blk, 0, stream>>>(nh_a, NowT, Nob, x, out_nh, st1,
                                                NN, 256, 256, 2);
  bn_fin_k<<<dim3(1), blk, 0, stream>>>(st1, 1.0f / NN);
  bn_apply_k<<<dim3(NN * 64 / 256), blk, 0, stream>>>(out_nh, nh2, st1,
                                                      bn1n_g, bn1n_b, (long)NN * 64);
  // FFN
  gemm_bf16_k<<<dim3(4, 157), blk, 0, stream>>>(nh2, f1wT, f1b, nullptr, ffn1, nullptr,
                                                NN, 256, 512, 1);
  gemm_bf16_k<<<dim3(2, 157), blk, 0, stream>>>(ffn1, f2wT, f2b, nh2, out_nh, st2,
                                                NN, 512, 256, 2);
  bn_fin_k<<<dim3(1), blk, 0, stream>>>(st2, 1.0f / NN);
  bn_apply_k<<<dim3(NN * 64 / 256), blk, 0, stream>>>(out_nh, out_nh, st2,
                                                      bn2_g, bn2_b, (long)NN * 64);
}